// Round 2
// baseline (25895.721 us; speedup 1.0000x reference)
//
#include <hip/hip_runtime.h>
#include <hip/hip_bf16.h>

// Problem constants
constexpr int B_ = 32, S_ = 300, D_ = 512, H_ = 8;
constexpr int L_ = 6, E_ = 6, F_ = 1024;
constexpr int CHORD_ = 159;
constexpr int R_ = B_ * S_;      // 9600 rows (tokens)
constexpr int TD_ = 3 * D_;      // 1536
constexpr int MT_ = R_ / 64;     // 150 row tiles per expert (worst case)

// ---------------- block reduction (sum, sumsq) over 256 threads ----------------
static __device__ __forceinline__ float2 blockReduce2(float s, float ss) {
    __shared__ float red[4][2];
    #pragma unroll
    for (int o = 32; o > 0; o >>= 1) { s += __shfl_down(s, o); ss += __shfl_down(ss, o); }
    const int wid = threadIdx.x >> 6, lane = threadIdx.x & 63;
    if (lane == 0) { red[wid][0] = s; red[wid][1] = ss; }
    __syncthreads();
    if (threadIdx.x == 0) {
        for (int w = 1; w < 4; ++w) { s += red[w][0]; ss += red[w][1]; }
        red[0][0] = s; red[0][1] = ss;
    }
    __syncthreads();
    return make_float2(red[0][0], red[0][1]);
}

// ---------------- generic GEMM: Y[m,n] = sum_k X[m,k]*W[n,k] + bias[n] (+pos[m%S,n]) ----------------
// X: f32 [R_, ldx]; W: f32 [N,K] row-major; out f32; tile 64x64x16.
__global__ __launch_bounds__(256) void gemm_xwT(
    const float* __restrict__ X, int ldx,
    const float* __restrict__ W, const float* __restrict__ bias,
    float* __restrict__ Yf, int ldy,
    int N, int K, const float* __restrict__ pos)
{
    __shared__ float Xs[16][68];
    __shared__ float Ws[16][68];
    const int m0 = blockIdx.x * 64, n0 = blockIdx.y * 64;
    const int tid = threadIdx.x;
    const int tx = tid & 15, ty = tid >> 4;
    float acc[4][4] = {};
    for (int k0 = 0; k0 < K; k0 += 16) {
        const int kk = tid & 15;
        const int kg = k0 + kk;
        const bool kok = kg < K;
        #pragma unroll
        for (int p = 0; p < 4; ++p) {
            const int mi = ty + p * 16;
            Xs[kk][mi] = kok ? X[(size_t)(m0 + mi) * ldx + kg] : 0.f;
        }
        #pragma unroll
        for (int p = 0; p < 4; ++p) {
            const int ni = ty + p * 16;
            const int ng = n0 + ni;
            Ws[kk][ni] = (kok && ng < N) ? W[(size_t)ng * K + kg] : 0.f;
        }
        __syncthreads();
        #pragma unroll
        for (int kk2 = 0; kk2 < 16; ++kk2) {
            const float4 xa = *(const float4*)&Xs[kk2][ty * 4];
            const float4 wb = *(const float4*)&Ws[kk2][tx * 4];
            const float xs[4] = {xa.x, xa.y, xa.z, xa.w};
            const float wv[4] = {wb.x, wb.y, wb.z, wb.w};
            #pragma unroll
            for (int a = 0; a < 4; ++a)
                #pragma unroll
                for (int bq = 0; bq < 4; ++bq)
                    acc[a][bq] += xs[a] * wv[bq];
        }
        __syncthreads();
    }
    #pragma unroll
    for (int a = 0; a < 4; ++a) {
        const int m = m0 + ty * 4 + a;
        #pragma unroll
        for (int bq = 0; bq < 4; ++bq) {
            const int n = n0 + tx * 4 + bq;
            if (n < N) {
                float y = acc[a][bq];
                if (bias) y += bias[n];
                if (pos)  y += pos[(size_t)(m % S_) * N + n];
                Yf[(size_t)m * ldy + n] = y;
            }
        }
    }
}

// ---------------- fused attention: one block per (b, head); thread = query row ----------------
// qkv: [R_, 1536] f32 (q | k | v, head-major 64 each). out: [R_, 512] f32.
template<bool CAUSAL>
__global__ __launch_bounds__(320) void attn_kern(const float* __restrict__ qkv, float* __restrict__ out)
{
    __shared__ float Ks[64][64];
    __shared__ float Vs[64][64];
    const int b = blockIdx.x >> 3, hh = blockIdx.x & 7;
    const int tid = threadIdx.x;
    const float* base = qkv + (size_t)b * S_ * TD_ + hh * 64;
    const bool act = tid < S_;
    float4 q4[16];
    if (act) {
        const float4* qp = (const float4*)(base + (size_t)tid * TD_);
        #pragma unroll
        for (int dd = 0; dd < 16; ++dd) q4[dd] = qp[dd];
    }
    float m = -3.0e38f;
    // pass A: exact row max
    for (int j0 = 0; j0 < S_; j0 += 64) {
        const int tn = min(64, S_ - j0);
        __syncthreads();
        for (int idx = tid; idx < 64 * 64; idx += 320) {
            const int jj = idx >> 6, d = idx & 63;
            Ks[jj][d] = (jj < tn) ? base[(size_t)(j0 + jj) * TD_ + D_ + d] : 0.f;
        }
        __syncthreads();
        if (act) {
            const int jmax = CAUSAL ? min(tn, tid - j0 + 1) : tn;
            for (int jj = 0; jj < jmax; ++jj) {
                const float4* kp = (const float4*)Ks[jj];
                float s = 0.f;
                #pragma unroll
                for (int dd = 0; dd < 16; ++dd) {
                    const float4 kv = kp[dd];
                    s += q4[dd].x * kv.x + q4[dd].y * kv.y + q4[dd].z * kv.z + q4[dd].w * kv.w;
                }
                m = fmaxf(m, s * 0.125f);
            }
        }
    }
    // pass B: exp-sum and AV accumulate
    float l = 0.f;
    float acc[64];
    #pragma unroll
    for (int d = 0; d < 64; ++d) acc[d] = 0.f;
    for (int j0 = 0; j0 < S_; j0 += 64) {
        const int tn = min(64, S_ - j0);
        __syncthreads();
        for (int idx = tid; idx < 64 * 64; idx += 320) {
            const int jj = idx >> 6, d = idx & 63;
            const bool ok = jj < tn;
            Ks[jj][d] = ok ? base[(size_t)(j0 + jj) * TD_ + D_ + d] : 0.f;
            Vs[jj][d] = ok ? base[(size_t)(j0 + jj) * TD_ + 2 * D_ + d] : 0.f;
        }
        __syncthreads();
        if (act) {
            const int jmax = CAUSAL ? min(tn, tid - j0 + 1) : tn;
            for (int jj = 0; jj < jmax; ++jj) {
                const float4* kp = (const float4*)Ks[jj];
                float s = 0.f;
                #pragma unroll
                for (int dd = 0; dd < 16; ++dd) {
                    const float4 kv = kp[dd];
                    s += q4[dd].x * kv.x + q4[dd].y * kv.y + q4[dd].z * kv.z + q4[dd].w * kv.w;
                }
                const float p = __expf(s * 0.125f - m);
                l += p;
                const float4* vp = (const float4*)Vs[jj];
                #pragma unroll
                for (int dd = 0; dd < 16; ++dd) {
                    const float4 vv = vp[dd];
                    acc[dd*4+0] += p * vv.x; acc[dd*4+1] += p * vv.y;
                    acc[dd*4+2] += p * vv.z; acc[dd*4+3] += p * vv.w;
                }
            }
        }
    }
    if (act) {
        const float inv = 1.f / l;
        float* op = out + (size_t)(b * S_ + tid) * D_ + hh * 64;
        #pragma unroll
        for (int d = 0; d < 64; ++d) op[d] = acc[d] * inv;
    }
}

// ---------------- LayerNorm kernels (block per row, 256 threads, 2 elems each) ----------------
__global__ __launch_bounds__(256) void add_ln_kern(float* __restrict__ h, const float* __restrict__ a,
    const float* __restrict__ g, const float* __restrict__ bb)
{
    const int r = blockIdx.x, tid = threadIdx.x;
    const size_t off = (size_t)r * D_;
    const float x0 = h[off + tid] + a[off + tid];
    const float x1 = h[off + tid + 256] + a[off + tid + 256];
    const float2 red = blockReduce2(x0 + x1, x0 * x0 + x1 * x1);
    const float mean = red.x * (1.f / D_);
    const float var = red.y * (1.f / D_) - mean * mean;
    const float rs = rsqrtf(var + 1e-5f);
    h[off + tid]       = (x0 - mean) * rs * g[tid]       + bb[tid];
    h[off + tid + 256] = (x1 - mean) * rs * g[tid + 256] + bb[tid + 256];
}

__global__ __launch_bounds__(256) void add2_ln_kern(float* __restrict__ h, const float* __restrict__ moeout,
    const float* __restrict__ g, const float* __restrict__ bb)
{
    const int r = blockIdx.x, tid = threadIdx.x;
    const size_t off = (size_t)r * D_;
    const size_t m0 = (size_t)(2 * r) * D_, m1 = (size_t)(2 * r + 1) * D_;
    const float x0 = h[off + tid]       + moeout[m0 + tid]       + moeout[m1 + tid];
    const float x1 = h[off + tid + 256] + moeout[m0 + tid + 256] + moeout[m1 + tid + 256];
    const float2 red = blockReduce2(x0 + x1, x0 * x0 + x1 * x1);
    const float mean = red.x * (1.f / D_);
    const float var = red.y * (1.f / D_) - mean * mean;
    const float rs = rsqrtf(var + 1e-5f);
    h[off + tid]       = (x0 - mean) * rs * g[tid]       + bb[tid];
    h[off + tid + 256] = (x1 - mean) * rs * g[tid + 256] + bb[tid + 256];
}

__global__ __launch_bounds__(256) void ln_kern(const float* __restrict__ src, float* __restrict__ dst,
    const float* __restrict__ g, const float* __restrict__ bb)
{
    const int r = blockIdx.x, tid = threadIdx.x;
    const size_t off = (size_t)r * D_;
    const float x0 = src[off + tid];
    const float x1 = src[off + tid + 256];
    const float2 red = blockReduce2(x0 + x1, x0 * x0 + x1 * x1);
    const float mean = red.x * (1.f / D_);
    const float var = red.y * (1.f / D_) - mean * mean;
    const float rs = rsqrtf(var + 1e-5f);
    dst[off + tid]       = (x0 - mean) * rs * g[tid]       + bb[tid];
    dst[off + tid + 256] = (x1 - mean) * rs * g[tid + 256] + bb[tid + 256];
}

// ---------------- input feature assembly ----------------
__global__ void assemble_chord(const int* __restrict__ x_root, const int* __restrict__ x_attr,
    const float* __restrict__ emb_root, const float* __restrict__ emb_attr,
    const float* __restrict__ fkey, float* __restrict__ Xa)
{
    const int idx = blockIdx.x * 256 + threadIdx.x;
    if (idx >= R_ * 513) return;
    const int r = idx / 513, k = idx - r * 513;
    float v;
    if (k < D_) v = emb_root[x_root[r] * D_ + k] + emb_attr[x_attr[r] * D_ + k];
    else        v = fkey[r / S_];
    Xa[idx] = v;
}

__global__ void assemble_vis(const float* __restrict__ fsem, const float* __restrict__ fscene,
    const float* __restrict__ fmotion, const float* __restrict__ femotion, float* __restrict__ Xa)
{
    const int idx = blockIdx.x * 256 + threadIdx.x;
    if (idx >= R_ * 776) return;
    const int r = idx / 776, k = idx - r * 776;
    float v;
    if (k < 768)       v = fsem[(size_t)r * 768 + k];
    else if (k == 768) v = fscene[r];
    else if (k == 769) v = fmotion[r];
    else               v = femotion[(size_t)r * 6 + (k - 770)];
    Xa[idx] = v;
}

// ---------------- MoE: routing (top-2 of 6, gather lists via atomics) ----------------
__global__ __launch_bounds__(256) void moe_route(const float* __restrict__ X,
    const float* __restrict__ gw, const float* __restrict__ gb,
    int* __restrict__ gcnt, int* __restrict__ gtok, float* __restrict__ gwt)
{
    const int t = blockIdx.x * 256 + threadIdx.x;
    if (t >= R_) return;
    float lg[E_];
    #pragma unroll
    for (int e = 0; e < E_; ++e) lg[e] = gb[e];
    const float* xp = X + (size_t)t * D_;
    for (int d = 0; d < D_; ++d) {
        const float xd = xp[d];
        #pragma unroll
        for (int e = 0; e < E_; ++e) lg[e] += xd * gw[e * D_ + d];
    }
    float mx = lg[0];
    #pragma unroll
    for (int e = 1; e < E_; ++e) mx = fmaxf(mx, lg[e]);
    float p[E_];
    #pragma unroll
    for (int e = 0; e < E_; ++e) p[e] = __expf(lg[e] - mx);
    int i1 = 0;
    #pragma unroll
    for (int e = 1; e < E_; ++e) if (p[e] > p[i1]) i1 = e;
    int i2 = (i1 == 0) ? 1 : 0;
    #pragma unroll
    for (int e = 0; e < E_; ++e) if (e != i1 && p[e] > p[i2]) i2 = e;
    const float denom = p[i1] + p[i2];
    const float w1 = p[i1] / denom, w2 = p[i2] / denom;
    int pos1 = atomicAdd(&gcnt[i1], 1);
    gtok[i1 * R_ + pos1] = t * 2;     gwt[i1 * R_ + pos1] = w1;
    int pos2 = atomicAdd(&gcnt[i2], 1);
    gtok[i2 * R_ + pos2] = t * 2 + 1; gwt[i2 * R_ + pos2] = w2;
}

// ---------------- MoE stage A: h1 = silu(x@w1+b1)*(x@w2+b2) for gathered rows ----------------
// w1,w2: [E, D, F] (k-major). grid.x = e*MT_+mt, grid.y = F/64.
__global__ __launch_bounds__(256) void moe_stageA(const float* __restrict__ X,
    const float* __restrict__ w1, const float* __restrict__ b1,
    const float* __restrict__ w2, const float* __restrict__ b2,
    const int* __restrict__ gcnt, const int* __restrict__ gtok, float* __restrict__ h1)
{
    const int e = blockIdx.x / MT_, mt = blockIdx.x % MT_;
    const int cnt = gcnt[e];
    const int m0 = mt * 64;
    if (m0 >= cnt) return;
    const int rows = min(64, cnt - m0);
    __shared__ int rid[64];
    __shared__ float Xs[16][68], W1s[16][68], W2s[16][68];
    const int tid = threadIdx.x;
    if (tid < 64) rid[tid] = (tid < rows) ? gtok[e * R_ + m0 + tid] : -1;
    __syncthreads();
    const int f0 = blockIdx.y * 64;
    float acc1[4][4] = {}, acc2[4][4] = {};
    const float* w1e = w1 + (size_t)e * D_ * F_;
    const float* w2e = w2 + (size_t)e * D_ * F_;
    const int ty = tid >> 4, tx = tid & 15;
    for (int k0 = 0; k0 < D_; k0 += 16) {
        const int kk = tid & 15;
        #pragma unroll
        for (int p = 0; p < 4; ++p) {
            const int mi = ty + p * 16;
            const int rr = rid[mi];
            Xs[kk][mi] = (rr >= 0) ? X[(size_t)(rr >> 1) * D_ + k0 + kk] : 0.f;
        }
        const int fi = tid & 63;
        #pragma unroll
        for (int p = 0; p < 4; ++p) {
            const int kw = (tid >> 6) + p * 4;
            const size_t off = (size_t)(k0 + kw) * F_ + f0 + fi;
            W1s[kw][fi] = w1e[off];
            W2s[kw][fi] = w2e[off];
        }
        __syncthreads();
        #pragma unroll
        for (int kk2 = 0; kk2 < 16; ++kk2) {
            const float4 xa = *(const float4*)&Xs[kk2][ty * 4];
            const float4 wa = *(const float4*)&W1s[kk2][tx * 4];
            const float4 wbv = *(const float4*)&W2s[kk2][tx * 4];
            const float xs[4] = {xa.x, xa.y, xa.z, xa.w};
            const float w1v[4] = {wa.x, wa.y, wa.z, wa.w};
            const float w2v[4] = {wbv.x, wbv.y, wbv.z, wbv.w};
            #pragma unroll
            for (int a = 0; a < 4; ++a)
                #pragma unroll
                for (int bq = 0; bq < 4; ++bq) {
                    acc1[a][bq] += xs[a] * w1v[bq];
                    acc2[a][bq] += xs[a] * w2v[bq];
                }
        }
        __syncthreads();
    }
    #pragma unroll
    for (int a = 0; a < 4; ++a) {
        const int mi = ty * 4 + a;
        const int rr = rid[mi];
        if (rr < 0) continue;
        #pragma unroll
        for (int bq = 0; bq < 4; ++bq) {
            const int f = f0 + tx * 4 + bq;
            const float a1 = acc1[a][bq] + b1[e * F_ + f];
            const float a2 = acc2[a][bq] + b2[e * F_ + f];
            const float sil = a1 / (1.f + __expf(-a1));
            h1[(size_t)rr * F_ + f] = sil * a2;
        }
    }
}

// ---------------- MoE stage B: moeout[slot] = wt*(h1@w3 + b3) ----------------
// w3: [E, F, D] (k-major). grid.x = e*MT_+mt, grid.y = D/64.
__global__ __launch_bounds__(256) void moe_stageB(const float* __restrict__ h1,
    const float* __restrict__ w3, const float* __restrict__ b3,
    const int* __restrict__ gcnt, const int* __restrict__ gtok, const float* __restrict__ gwt,
    float* __restrict__ moeout)
{
    const int e = blockIdx.x / MT_, mt = blockIdx.x % MT_;
    const int cnt = gcnt[e];
    const int m0 = mt * 64;
    if (m0 >= cnt) return;
    const int rows = min(64, cnt - m0);
    __shared__ int rid[64];
    __shared__ float wts[64];
    __shared__ float Xs[16][68], Ws[16][68];
    const int tid = threadIdx.x;
    if (tid < 64) {
        rid[tid] = (tid < rows) ? gtok[e * R_ + m0 + tid] : -1;
        wts[tid] = (tid < rows) ? gwt[e * R_ + m0 + tid] : 0.f;
    }
    __syncthreads();
    const int n0 = blockIdx.y * 64;
    float acc[4][4] = {};
    const float* w3e = w3 + (size_t)e * F_ * D_;
    const int ty = tid >> 4, tx = tid & 15;
    for (int k0 = 0; k0 < F_; k0 += 16) {
        const int kk = tid & 15;
        #pragma unroll
        for (int p = 0; p < 4; ++p) {
            const int mi = ty + p * 16;
            const int rr = rid[mi];
            Xs[kk][mi] = (rr >= 0) ? h1[(size_t)rr * F_ + k0 + kk] : 0.f;
        }
        const int ni = tid & 63;
        #pragma unroll
        for (int p = 0; p < 4; ++p) {
            const int kw = (tid >> 6) + p * 4;
            Ws[kw][ni] = w3e[(size_t)(k0 + kw) * D_ + n0 + ni];
        }
        __syncthreads();
        #pragma unroll
        for (int kk2 = 0; kk2 < 16; ++kk2) {
            const float4 xa = *(const float4*)&Xs[kk2][ty * 4];
            const float4 wb = *(const float4*)&Ws[kk2][tx * 4];
            const float xs[4] = {xa.x, xa.y, xa.z, xa.w};
            const float wv[4] = {wb.x, wb.y, wb.z, wb.w};
            #pragma unroll
            for (int a = 0; a < 4; ++a)
                #pragma unroll
                for (int bq = 0; bq < 4; ++bq)
                    acc[a][bq] += xs[a] * wv[bq];
        }
        __syncthreads();
    }
    #pragma unroll
    for (int a = 0; a < 4; ++a) {
        const int mi = ty * 4 + a;
        const int rr = rid[mi];
        if (rr < 0) continue;
        const float wt = wts[mi];
        #pragma unroll
        for (int bq = 0; bq < 4; ++bq) {
            const int n = n0 + tx * 4 + bq;
            moeout[(size_t)rr * D_ + n] = wt * (acc[a][bq] + b3[e * D_ + n]);
        }
    }
}

// =========================================================================================
extern "C" void kernel_launch(void* const* d_in, const int* in_sizes, int n_in,
                              void* d_out, int out_size, void* d_ws, size_t ws_size,
                              hipStream_t stream) {
    (void)in_sizes; (void)n_in; (void)out_size; (void)ws_size;
    // inputs, setup_inputs() dict order (all floats are float32 device buffers)
    const int*   x_root    = (const int*)  d_in[1];
    const int*   x_attr    = (const int*)  d_in[2];
    const float* fsem      = (const float*)d_in[3];
    const float* fkey      = (const float*)d_in[4];
    const float* fscene    = (const float*)d_in[5];
    const float* fmotion   = (const float*)d_in[6];
    const float* femotion  = (const float*)d_in[7];
    const float* emb_root  = (const float*)d_in[8];
    const float* emb_attr  = (const float*)d_in[9];
    const float* w_chord   = (const float*)d_in[10];
    const float* b_chord   = (const float*)d_in[11];
    const float* w_vis     = (const float*)d_in[12];
    const float* b_vis     = (const float*)d_in[13];
    const float* pos_c     = (const float*)d_in[14];
    const float* pos_v     = (const float*)d_in[15];
    const float* enc_qkv_w = (const float*)d_in[16];
    const float* enc_qkv_b = (const float*)d_in[17];
    const float* enc_ow    = (const float*)d_in[18];
    const float* enc_ob    = (const float*)d_in[19];
    const float* dec_sqkv_w= (const float*)d_in[20];
    const float* dec_sqkv_b= (const float*)d_in[21];
    const float* dec_sow   = (const float*)d_in[22];
    const float* dec_sob   = (const float*)d_in[23];
    const float* dec_cqkv_w= (const float*)d_in[24];
    const float* dec_cqkv_b= (const float*)d_in[25];
    const float* dec_cow   = (const float*)d_in[26];
    const float* dec_cob   = (const float*)d_in[27];
    const float* enc_gw    = (const float*)d_in[28];
    const float* enc_gb    = (const float*)d_in[29];
    const float* enc_w1    = (const float*)d_in[30];
    const float* enc_b1    = (const float*)d_in[31];
    const float* enc_w2    = (const float*)d_in[32];
    const float* enc_b2    = (const float*)d_in[33];
    const float* enc_w3    = (const float*)d_in[34];
    const float* enc_b3    = (const float*)d_in[35];
    const float* dec_gw    = (const float*)d_in[36];
    const float* dec_gb    = (const float*)d_in[37];
    const float* dec_w1    = (const float*)d_in[38];
    const float* dec_b1    = (const float*)d_in[39];
    const float* dec_w2    = (const float*)d_in[40];
    const float* dec_b2    = (const float*)d_in[41];
    const float* dec_w3    = (const float*)d_in[42];
    const float* dec_b3    = (const float*)d_in[43];
    const float* enc_ln1_g = (const float*)d_in[44];
    const float* enc_ln1_b = (const float*)d_in[45];
    const float* enc_ln2_g = (const float*)d_in[46];
    const float* enc_ln2_b = (const float*)d_in[47];
    const float* dec_ln1_g = (const float*)d_in[48];
    const float* dec_ln1_b = (const float*)d_in[49];
    const float* dec_ln2_g = (const float*)d_in[50];
    const float* dec_ln2_b = (const float*)d_in[51];
    const float* dec_ln3_g = (const float*)d_in[52];
    const float* dec_ln3_b = (const float*)d_in[53];
    const float* enc_fg    = (const float*)d_in[54];
    const float* enc_fb    = (const float*)d_in[55];
    const float* dec_fg    = (const float*)d_in[56];
    const float* dec_fb    = (const float*)d_in[57];
    const float* wout      = (const float*)d_in[58];
    const float* bout      = (const float*)d_in[59];

    // workspace layout (~197 MB, all f32)
    float* h    = (float*)d_ws;                      // [R_, D]   current hidden
    float* tmp  = h    + (size_t)R_ * D_;            // [R_, D]   attn out
    float* qkvb = tmp  + (size_t)R_ * D_;            // [R_, 3D]  qkv / assembled feats / proj out / moeout
    float* memb = qkvb + (size_t)R_ * TD_;           // [R_, D]   encoder memory
    float* h1   = memb + (size_t)R_ * D_;            // [2R_, F]  MoE hidden
    int*   gcnt = (int*)(h1 + (size_t)2 * R_ * F_);  // [E]
    int*   gtok = gcnt + 16;                         // [E*R_]
    float* gwt  = (float*)(gtok + E_ * R_);          // [E*R_]

    auto gemm = [&](const float* X, int ldx, const float* W, const float* bias,
                    float* Yf, int ldy, int N, int K, const float* pos) {
        dim3 g(R_ / 64, (N + 63) / 64);
        gemm_xwT<<<g, dim3(256), 0, stream>>>(X, ldx, W, bias, Yf, ldy, N, K, pos);
    };
    auto run_moe = [&](const float* gw, const float* gb,
                       const float* w1, const float* b1, const float* w2, const float* b2,
                       const float* w3, const float* b3, const float* lng, const float* lnb) {
        hipMemsetAsync(gcnt, 0, 16 * sizeof(int), stream);
        moe_route<<<dim3((R_ + 255) / 256), dim3(256), 0, stream>>>(h, gw, gb, gcnt, gtok, gwt);
        moe_stageA<<<dim3(E_ * MT_, F_ / 64), dim3(256), 0, stream>>>(h, w1, b1, w2, b2, gcnt, gtok, h1);
        moe_stageB<<<dim3(E_ * MT_, D_ / 64), dim3(256), 0, stream>>>(h1, w3, b3, gcnt, gtok, gwt, qkvb);
        add2_ln_kern<<<dim3(R_), dim3(256), 0, stream>>>(h, qkvb, lng, lnb);
    };

    // ---- encoder input: vf = vfc @ w_vis.T + b_vis + pos_v ----
    assemble_vis<<<dim3((R_ * 776 + 255) / 256), dim3(256), 0, stream>>>(fsem, fscene, fmotion, femotion, qkvb);
    gemm(qkvb, 776, w_vis, b_vis, h, D_, D_, 776, pos_v);

    // ---- encoder layers ----
    for (int i = 0; i < L_; ++i) {
        gemm(h, D_, enc_qkv_w + (size_t)i * TD_ * D_, enc_qkv_b + (size_t)i * TD_, qkvb, TD_, TD_, D_, nullptr);
        attn_kern<false><<<dim3(B_ * H_), dim3(320), 0, stream>>>(qkvb, tmp);
        gemm(tmp, D_, enc_ow + (size_t)i * D_ * D_, enc_ob + (size_t)i * D_, qkvb, D_, D_, D_, nullptr);
        add_ln_kern<<<dim3(R_), dim3(256), 0, stream>>>(h, qkvb, enc_ln1_g + i * D_, enc_ln1_b + i * D_);
        run_moe(enc_gw + (size_t)i * E_ * D_, enc_gb + (size_t)i * E_,
                enc_w1 + (size_t)i * E_ * D_ * F_, enc_b1 + (size_t)i * E_ * F_,
                enc_w2 + (size_t)i * E_ * D_ * F_, enc_b2 + (size_t)i * E_ * F_,
                enc_w3 + (size_t)i * E_ * F_ * D_, enc_b3 + (size_t)i * E_ * D_,
                enc_ln2_g + i * D_, enc_ln2_b + i * D_);
    }
    ln_kern<<<dim3(R_), dim3(256), 0, stream>>>(h, memb, enc_fg, enc_fb);

    // ---- decoder input: xf = [emb_root+emb_attr | key] @ w_chord.T + b_chord + pos_c ----
    assemble_chord<<<dim3((R_ * 513 + 255) / 256), dim3(256), 0, stream>>>(x_root, x_attr, emb_root, emb_attr, fkey, qkvb);
    gemm(qkvb, 513, w_chord, b_chord, h, D_, D_, 513, pos_c);

    // ---- decoder layers ----
    for (int i = 0; i < L_; ++i) {
        // masked self-attention
        gemm(h, D_, dec_sqkv_w + (size_t)i * TD_ * D_, dec_sqkv_b + (size_t)i * TD_, qkvb, TD_, TD_, D_, nullptr);
        attn_kern<true><<<dim3(B_ * H_), dim3(320), 0, stream>>>(qkvb, tmp);
        gemm(tmp, D_, dec_sow + (size_t)i * D_ * D_, dec_sob + (size_t)i * D_, qkvb, D_, D_, D_, nullptr);
        add_ln_kern<<<dim3(R_), dim3(256), 0, stream>>>(h, qkvb, dec_ln1_g + i * D_, dec_ln1_b + i * D_);
        // cross-attention: q from h, k/v from encoder memory
        gemm(h, D_, dec_cqkv_w + (size_t)i * TD_ * D_, dec_cqkv_b + (size_t)i * TD_, qkvb, TD_, D_, D_, nullptr);
        gemm(memb, D_, dec_cqkv_w + ((size_t)i * TD_ + D_) * D_, dec_cqkv_b + (size_t)i * TD_ + D_,
             qkvb + D_, TD_, 2 * D_, D_, nullptr);
        attn_kern<false><<<dim3(B_ * H_), dim3(320), 0, stream>>>(qkvb, tmp);
        gemm(tmp, D_, dec_cow + (size_t)i * D_ * D_, dec_cob + (size_t)i * D_, qkvb, D_, D_, D_, nullptr);
        add_ln_kern<<<dim3(R_), dim3(256), 0, stream>>>(h, qkvb, dec_ln2_g + i * D_, dec_ln2_b + i * D_);
        // MoE
        run_moe(dec_gw + (size_t)i * E_ * D_, dec_gb + (size_t)i * E_,
                dec_w1 + (size_t)i * E_ * D_ * F_, dec_b1 + (size_t)i * E_ * F_,
                dec_w2 + (size_t)i * E_ * D_ * F_, dec_b2 + (size_t)i * E_ * F_,
                dec_w3 + (size_t)i * E_ * F_ * D_, dec_b3 + (size_t)i * E_ * D_,
                dec_ln3_g + i * D_, dec_ln3_b + i * D_);
    }

    // ---- final LN + output projection (f32 out) ----
    ln_kern<<<dim3(R_), dim3(256), 0, stream>>>(h, tmp, dec_fg, dec_fb);
    gemm(tmp, D_, wout, bout, (float*)d_out, CHORD_, CHORD_, D_, nullptr);
}